// Round 1
// baseline (898.747 us; speedup 1.0000x reference)
//
#include <hip/hip_runtime.h>

// Shapes (fixed by the reference):
// B=16, S=512, L=12, H=12, DH=64, D=768, M=13
// mlp_stack  [16,512,13,768] f32
// attn_stack [16,512,12,12,64] f32  == A rows (b,s)=8192 x K=9216 row-major
// mlp_mask   [16,13] f32
// attn_mask  [16,12,12] f32
// modal_mlp  [13,768] f32
// modal_att  [12,12,768] f32
// W_O        [12,12,64,768] f32 == [K=9216][N=768] row-major
// post_bias  [12,768] f32
// out        [16,512,768] f32

#define D_ 768
#define K_ 9216
#define ROWS_ 8192   // B*S

typedef __attribute__((ext_vector_type(8))) short short8;
typedef __attribute__((ext_vector_type(4))) float f32x4;

typedef unsigned int __attribute__((address_space(1))) gu32;
typedef unsigned int __attribute__((address_space(3))) lu32;

__device__ __forceinline__ void async_copy16(const void* g, void* l) {
    __builtin_amdgcn_global_load_lds((const gu32*)g, (lu32*)l, 16, 0, 0);
}

// round-to-nearest-even f32 -> bf16 (inputs are finite; no NaN handling needed)
__device__ __forceinline__ unsigned short f2bf(float f) {
    union { float f; unsigned u; } a; a.f = f;
    unsigned r = a.u + 0x7FFF + ((a.u >> 16) & 1);
    return (unsigned short)(r >> 16);
}

// ---------------- K0: per-batch bias ----------------
// bias[b][d] = sum_p post_bias[p][d] + sum_m (1-mlp_mask[b,m])*modal_mlp[m,d]
//            + sum_ph (1-attn_mask[b,ph])*modal_att[ph,d]
__global__ __launch_bounds__(256) void bias_kernel(
    const float* __restrict__ mlp_mask, const float* __restrict__ attn_mask,
    const float* __restrict__ modal_mlp, const float* __restrict__ modal_att,
    const float* __restrict__ post_bias, float* __restrict__ bias) {
    int b = blockIdx.x;
    for (int d = threadIdx.x; d < D_; d += 256) {
        float acc = 0.f;
        #pragma unroll
        for (int p = 0; p < 12; ++p) acc += post_bias[p * D_ + d];
        #pragma unroll
        for (int m = 0; m < 13; ++m)
            acc += (1.f - mlp_mask[b * 13 + m]) * modal_mlp[m * D_ + d];
        for (int ph = 0; ph < 144; ++ph)
            acc += (1.f - attn_mask[b * 144 + ph]) * modal_att[ph * D_ + d];
        bias[b * D_ + d] = acc;
    }
}

// ---------------- K1: transpose-convert W_O [9216,768] f32 -> Bt [768,9216] bf16 ----------------
__global__ __launch_bounds__(256) void transpose_wo(
    const float* __restrict__ W, unsigned short* __restrict__ Bt) {
    __shared__ float tile[32][33];
    int n0 = blockIdx.x * 32;   // 24 tiles over N
    int k0 = blockIdx.y * 32;   // 288 tiles over K
    int tx = threadIdx.x & 31, ty = threadIdx.x >> 5;
    #pragma unroll
    for (int i = 0; i < 4; ++i)
        tile[ty + 8 * i][tx] = W[(k0 + ty + 8 * i) * D_ + n0 + tx];
    __syncthreads();
    #pragma unroll
    for (int i = 0; i < 4; ++i)
        Bt[(n0 + ty + 8 * i) * K_ + k0 + tx] = f2bf(tile[tx][ty + 8 * i]);
}

// ---------------- K2: mask+convert attn_stack f32 -> A bf16 ----------------
// 9 blocks per row (9216/4/256 = 9)
__global__ __launch_bounds__(256) void conv_attn(
    const float* __restrict__ attn_stack, const float* __restrict__ attn_mask,
    unsigned short* __restrict__ A) {
    int bid = blockIdx.x;
    int row = bid / 9;
    int k = ((bid - row * 9) * 256 + threadIdx.x) * 4;
    int b = row >> 9;
    float w = attn_mask[b * 144 + (k >> 6)];
    int i = row * K_ + k;  // < 75.5M, fits int
    float4 v = *(const float4*)&attn_stack[i];
    ushort4 o;
    o.x = f2bf(v.x * w); o.y = f2bf(v.y * w);
    o.z = f2bf(v.z * w); o.w = f2bf(v.w * w);
    *(ushort4*)&A[i] = o;
}

// ---------------- K3: out = bias + sum_m mlp_mask*mlp_stack ----------------
__global__ __launch_bounds__(256) void mlp_kernel(
    const float* __restrict__ mlp_stack, const float* __restrict__ mlp_mask,
    const float* __restrict__ bias, float* __restrict__ out) {
    int i4 = (blockIdx.x * 256 + threadIdx.x) * 4;   // < 6.3M, fits int
    int row = i4 / D_;
    int d = i4 - row * D_;
    int b = row >> 9;
    float4 acc = *(const float4*)&bias[b * D_ + d];
    const float* base = mlp_stack + (long)row * 13 * D_ + d;
    #pragma unroll
    for (int m = 0; m < 13; ++m) {
        float w = mlp_mask[b * 13 + m];
        float4 v = *(const float4*)&base[m * D_];
        acc.x += w * v.x; acc.y += w * v.y;
        acc.z += w * v.z; acc.w += w * v.w;
    }
    *(float4*)&out[i4] = acc;
}

// ---------------- K4: out += A[8192x9216] * Bt^T  (bf16 MFMA, m97 structure) ----------------
// 128x128 tile, BK=32, 256 threads = 4 waves in 2x2, each wave 64x64 via 4x4 MFMA 16x16x32.
// LDS: As[128][32] bf16 (64B rows), Bs[128 n][32 k] bf16. No padding (global_load_lds),
// XOR-swizzle of 16B granules within each row: LDS[row][x] holds global granule x ^ ((row>>1)&3).
__global__ __launch_bounds__(256) void gemm_attn(
    const short* __restrict__ A, const short* __restrict__ Bt,
    float* __restrict__ out) {
    __shared__ __align__(16) short As[128 * 32];
    __shared__ __align__(16) short Bs[128 * 32];

    const int tid = threadIdx.x;
    const int wave = tid >> 6, lane = tid & 63;
    const int row0 = blockIdx.x * 128;   // over M=8192 (64 tiles)
    const int col0 = blockIdx.y * 128;   // over N=768  (6 tiles)
    const int wr = (wave >> 1) * 64;
    const int wc = (wave & 1) * 64;

    f32x4 acc[4][4] = {};

    // staging: chunk c = wave*2+j covers rows c*16..c*16+15 (1024B), lane -> rc=lane>>2, x=lane&3
    const int rc = lane >> 2;
    const int x = lane & 3;
    const int g = x ^ ((rc >> 1) & 3);   // swizzled global granule

    int a_off[2], b_off[2], lds_off[2];
    #pragma unroll
    for (int j = 0; j < 2; ++j) {
        int c = wave * 2 + j;
        a_off[j] = (row0 + c * 16 + rc) * K_ + g * 8;
        b_off[j] = (col0 + c * 16 + rc) * K_ + g * 8;
        lds_off[j] = c * 1024;           // bytes, wave-uniform
    }

    // fragment read: row = wr+i*16+fr, wants granule q=lane>>4 at pos q^((fr>>1)&3)
    const int fr = lane & 15;
    const int q = lane >> 4;
    const int pos = q ^ ((fr >> 1) & 3);

    for (int k0 = 0; k0 < K_; k0 += 32) {
        __syncthreads();
        #pragma unroll
        for (int j = 0; j < 2; ++j) {
            async_copy16(A + a_off[j] + k0, (char*)As + lds_off[j]);
            async_copy16(Bt + b_off[j] + k0, (char*)Bs + lds_off[j]);
        }
        __syncthreads();  // compiler emits s_waitcnt vmcnt(0) before s_barrier

        short8 af[4], bf[4];
        #pragma unroll
        for (int i = 0; i < 4; ++i) {
            af[i] = *(const short8*)&As[(wr + i * 16 + fr) * 32 + pos * 8];
            bf[i] = *(const short8*)&Bs[(wc + i * 16 + fr) * 32 + pos * 8];
        }
        #pragma unroll
        for (int i = 0; i < 4; ++i)
            #pragma unroll
            for (int j = 0; j < 4; ++j)
                acc[i][j] = __builtin_amdgcn_mfma_f32_16x16x32_bf16(
                    af[i], bf[j], acc[i][j], 0, 0, 0);
    }

    // epilogue: D row m = quad*4+reg, col n = lane&15 ; out += acc
    #pragma unroll
    for (int i = 0; i < 4; ++i) {
        int m = row0 + wr + i * 16 + q * 4;
        #pragma unroll
        for (int j = 0; j < 4; ++j) {
            int n = col0 + wc + j * 16 + fr;
            float* p = out + m * D_ + n;
            #pragma unroll
            for (int r = 0; r < 4; ++r)
                p[r * D_] += acc[i][j][r];
        }
    }
}

extern "C" void kernel_launch(void* const* d_in, const int* in_sizes, int n_in,
                              void* d_out, int out_size, void* d_ws, size_t ws_size,
                              hipStream_t stream) {
    const float* mlp_stack  = (const float*)d_in[0];
    const float* attn_stack = (const float*)d_in[1];
    const float* mlp_mask   = (const float*)d_in[2];
    const float* attn_mask  = (const float*)d_in[3];
    const float* modal_mlp  = (const float*)d_in[4];
    const float* modal_att  = (const float*)d_in[5];
    const float* W_O        = (const float*)d_in[6];
    const float* post_bias  = (const float*)d_in[7];
    float* out = (float*)d_out;

    char* ws = (char*)d_ws;
    unsigned short* Abf = (unsigned short*)ws;                         // 8192*9216*2 = 150,994,944 B
    unsigned short* Btb = (unsigned short*)(ws + 150994944);           // 768*9216*2  =  14,155,776 B
    float* bias = (float*)(ws + 150994944 + 14155776);                 // 16*768*4    =      49,152 B

    bias_kernel<<<16, 256, 0, stream>>>(mlp_mask, attn_mask, modal_mlp,
                                        modal_att, post_bias, bias);
    transpose_wo<<<dim3(24, 288), 256, 0, stream>>>(W_O, Btb);
    conv_attn<<<73728, 256, 0, stream>>>(attn_stack, attn_mask, Abf);
    mlp_kernel<<<6144, 256, 0, stream>>>(mlp_stack, mlp_mask, bias, out);
    gemm_attn<<<dim3(64, 6), 256, 0, stream>>>((const short*)Abf, (const short*)Btb, out);
}

// Round 2
// 893.388 us; speedup vs baseline: 1.0060x; 1.0060x over previous
//
#include <hip/hip_runtime.h>

// Shapes (fixed by the reference):
// B=16, S=512, L=12, H=12, DH=64, D=768, M=13
// attn GEMM: A rows (b,s)=8192 x K=9216, W_O = [K=9216][N=768]

#define D_ 768
#define K_ 9216
#define ROWS_ 8192   // B*S
#define SPLITS 4
#define KSPLIT (K_ / SPLITS)   // 2304

typedef __attribute__((ext_vector_type(8))) short short8;
typedef __attribute__((ext_vector_type(8))) unsigned short ushort8;
typedef __attribute__((ext_vector_type(4))) float f32x4;

typedef unsigned int __attribute__((address_space(1))) gu32;
typedef unsigned int __attribute__((address_space(3))) lu32;

__device__ __forceinline__ void async_copy16(const void* g, void* l) {
    __builtin_amdgcn_global_load_lds((const gu32*)g, (lu32*)l, 16, 0, 0);
}

// round-to-nearest-even f32 -> bf16 (finite inputs)
__device__ __forceinline__ unsigned short f2bf(float f) {
    union { float f; unsigned u; } a; a.f = f;
    unsigned r = a.u + 0x7FFF + ((a.u >> 16) & 1);
    return (unsigned short)(r >> 16);
}

// ---------------- K0: per-batch bias, parallel over d ----------------
__global__ __launch_bounds__(256) void bias_kernel(
    const float* __restrict__ mlp_mask, const float* __restrict__ attn_mask,
    const float* __restrict__ modal_mlp, const float* __restrict__ modal_att,
    const float* __restrict__ post_bias, float* __restrict__ bias) {
    int b = blockIdx.x;
    int d = blockIdx.y * 256 + threadIdx.x;
    float acc = 0.f;
    #pragma unroll
    for (int p = 0; p < 12; ++p) acc += post_bias[p * D_ + d];
    #pragma unroll
    for (int m = 0; m < 13; ++m)
        acc += (1.f - mlp_mask[b * 13 + m]) * modal_mlp[m * D_ + d];
    #pragma unroll 16
    for (int ph = 0; ph < 144; ++ph)
        acc += (1.f - attn_mask[b * 144 + ph]) * modal_att[ph * D_ + d];
    bias[b * D_ + d] = acc;
}

// ---------------- K1: transpose-convert W_O [9216,768] f32 -> Bt [768,9216] bf16 ----------------
__global__ __launch_bounds__(256) void transpose_wo(
    const float* __restrict__ W, unsigned short* __restrict__ Bt) {
    __shared__ float tile[32][33];
    int n0 = blockIdx.x * 32;
    int k0 = blockIdx.y * 32;
    int tx = threadIdx.x & 31, ty = threadIdx.x >> 5;
    #pragma unroll
    for (int i = 0; i < 4; ++i)
        tile[ty + 8 * i][tx] = W[(k0 + ty + 8 * i) * D_ + n0 + tx];
    __syncthreads();
    #pragma unroll
    for (int i = 0; i < 4; ++i)
        Bt[(n0 + ty + 8 * i) * K_ + k0 + tx] = f2bf(tile[tx][ty + 8 * i]);
}

// ---------------- K2: mask+convert attn_stack f32 -> A bf16, 8 elems/thread ----------------
__global__ __launch_bounds__(256) void conv_attn(
    const float* __restrict__ attn_stack, const float* __restrict__ attn_mask,
    unsigned short* __restrict__ A) {
    int i = (blockIdx.x * 256 + threadIdx.x) * 8;   // < 75.5M, fits int
    int row = i / K_;
    int k = i - row * K_;
    int b = row >> 9;
    float w = attn_mask[b * 144 + (k >> 6)];        // k 8-aligned: one (p,h) group
    float4 v0 = *(const float4*)&attn_stack[i];
    float4 v1 = *(const float4*)&attn_stack[i + 4];
    ushort8 o;
    o[0] = f2bf(v0.x * w); o[1] = f2bf(v0.y * w);
    o[2] = f2bf(v0.z * w); o[3] = f2bf(v0.w * w);
    o[4] = f2bf(v1.x * w); o[5] = f2bf(v1.y * w);
    o[6] = f2bf(v1.z * w); o[7] = f2bf(v1.w * w);
    *(ushort8*)&A[i] = o;
}

// ---------------- K3: out = bias + sum_m mlp_mask*mlp_stack ----------------
__global__ __launch_bounds__(256) void mlp_kernel(
    const float* __restrict__ mlp_stack, const float* __restrict__ mlp_mask,
    const float* __restrict__ bias, float* __restrict__ out) {
    int i4 = (blockIdx.x * 256 + threadIdx.x) * 4;
    int row = i4 / D_;
    int d = i4 - row * D_;
    int b = row >> 9;
    float4 acc = *(const float4*)&bias[b * D_ + d];
    const float* base = mlp_stack + (long)row * 13 * D_ + d;
    #pragma unroll
    for (int m = 0; m < 13; ++m) {
        float w = mlp_mask[b * 13 + m];
        float4 v = *(const float4*)&base[m * D_];
        acc.x += w * v.x; acc.y += w * v.y;
        acc.z += w * v.z; acc.w += w * v.w;
    }
    *(float4*)&out[i4] = acc;
}

// ---------------- K4: out += A[8192x9216] * Bt^T, split-K, bf16 MFMA ----------------
// 128x128 tile, BK=32, 4 waves 2x2, wave 64x64 via 4x4 MFMA 16x16x32.
// grid (64, 6, SPLITS); each z handles K range [z*KSPLIT, (z+1)*KSPLIT); atomic epilogue.
__global__ __launch_bounds__(256) void gemm_attn(
    const short* __restrict__ A, const short* __restrict__ Bt,
    float* __restrict__ out) {
    __shared__ __align__(16) short As[128 * 32];
    __shared__ __align__(16) short Bs[128 * 32];

    const int tid = threadIdx.x;
    const int wave = tid >> 6, lane = tid & 63;
    const int row0 = blockIdx.x * 128;
    const int col0 = blockIdx.y * 128;
    const int kStart = blockIdx.z * KSPLIT;
    const int wr = (wave >> 1) * 64;
    const int wc = (wave & 1) * 64;

    f32x4 acc[4][4] = {};

    // staging: chunk c = wave*2+j covers rows c*16..c*16+15; lane -> rc=lane>>2, x=lane&3
    const int rc = lane >> 2;
    const int x = lane & 3;
    const int g = x ^ ((rc >> 1) & 3);   // XOR-swizzled 16B granule

    int a_off[2], b_off[2], lds_off[2];
    #pragma unroll
    for (int j = 0; j < 2; ++j) {
        int c = wave * 2 + j;
        a_off[j] = (row0 + c * 16 + rc) * K_ + g * 8 + kStart;
        b_off[j] = (col0 + c * 16 + rc) * K_ + g * 8 + kStart;
        lds_off[j] = c * 1024;           // bytes, wave-uniform
    }

    const int fr = lane & 15;
    const int q = lane >> 4;
    const int pos = q ^ ((fr >> 1) & 3);

    for (int k0 = 0; k0 < KSPLIT; k0 += 32) {
        __syncthreads();
        #pragma unroll
        for (int j = 0; j < 2; ++j) {
            async_copy16(A + a_off[j] + k0, (char*)As + lds_off[j]);
            async_copy16(Bt + b_off[j] + k0, (char*)Bs + lds_off[j]);
        }
        __syncthreads();

        short8 af[4], bf[4];
        #pragma unroll
        for (int i = 0; i < 4; ++i) {
            af[i] = *(const short8*)&As[(wr + i * 16 + fr) * 32 + pos * 8];
            bf[i] = *(const short8*)&Bs[(wc + i * 16 + fr) * 32 + pos * 8];
        }
        #pragma unroll
        for (int i = 0; i < 4; ++i)
            #pragma unroll
            for (int j = 0; j < 4; ++j)
                acc[i][j] = __builtin_amdgcn_mfma_f32_16x16x32_bf16(
                    af[i], bf[j], acc[i][j], 0, 0, 0);
    }

    // epilogue: D row m = q*4+reg, col n = lane&15 ; atomic accumulate
    #pragma unroll
    for (int i = 0; i < 4; ++i) {
        int m = row0 + wr + i * 16 + q * 4;
        #pragma unroll
        for (int j = 0; j < 4; ++j) {
            int n = col0 + wc + j * 16 + fr;
            float* p = out + m * D_ + n;
            #pragma unroll
            for (int r = 0; r < 4; ++r)
                atomicAdd(p + r * D_, acc[i][j][r]);
        }
    }
}

extern "C" void kernel_launch(void* const* d_in, const int* in_sizes, int n_in,
                              void* d_out, int out_size, void* d_ws, size_t ws_size,
                              hipStream_t stream) {
    const float* mlp_stack  = (const float*)d_in[0];
    const float* attn_stack = (const float*)d_in[1];
    const float* mlp_mask   = (const float*)d_in[2];
    const float* attn_mask  = (const float*)d_in[3];
    const float* modal_mlp  = (const float*)d_in[4];
    const float* modal_att  = (const float*)d_in[5];
    const float* W_O        = (const float*)d_in[6];
    const float* post_bias  = (const float*)d_in[7];
    float* out = (float*)d_out;

    char* ws = (char*)d_ws;
    unsigned short* Abf = (unsigned short*)ws;                 // 150,994,944 B
    unsigned short* Btb = (unsigned short*)(ws + 150994944);   //  14,155,776 B
    float* bias = (float*)(ws + 150994944 + 14155776);         //      49,152 B

    bias_kernel<<<dim3(16, 3), 256, 0, stream>>>(mlp_mask, attn_mask, modal_mlp,
                                                 modal_att, post_bias, bias);
    transpose_wo<<<dim3(24, 288), 256, 0, stream>>>(W_O, Btb);
    conv_attn<<<36864, 256, 0, stream>>>(attn_stack, attn_mask, Abf);
    mlp_kernel<<<6144, 256, 0, stream>>>(mlp_stack, mlp_mask, bias, out);
    gemm_attn<<<dim3(64, 6, SPLITS), 256, 0, stream>>>((const short*)Abf,
                                                       (const short*)Btb, out);
}